// Round 19
// baseline (392.537 us; speedup 1.0000x reference)
//
#include <hip/hip_runtime.h>
#include <cstdint>

#define N_EMB 6272      // B*W*H = 8*28*28
#define DIMD  128
#define M_BANK 16384
#define BATCH 8
#define PPB   784       // patches per batch
#define KNN   9
#define EPSF  1e-12f
#define NKB   64        // scan blocks per batch (nn_find / knn)

typedef unsigned long long u64;
typedef _Float16 f16x8 __attribute__((ext_vector_type(8)));
typedef _Float16 f16x2 __attribute__((ext_vector_type(2)));
typedef float    f32x4 __attribute__((ext_vector_type(4)));

static __device__ __forceinline__ u64 umin64(u64 a, u64 b) { return b < a ? b : a; }
static __device__ __forceinline__ u64 umax64(u64 a, u64 b) { return b > a ? b : a; }

// async global->LDS, 16B per lane, linear LDS dest (wave-uniform base + lane*16)
static __device__ __forceinline__ void gll16(const _Float16* g, _Float16* l) {
    __builtin_amdgcn_global_load_lds(
        (__attribute__((address_space(1))) void*)(const void*)g,
        (__attribute__((address_space(3))) void*)l, 16, 0, 0);
}

// packed fp16 dot: 8 elems into fp32 accumulator
static __device__ __forceinline__ float dot8(f16x8 a, f16x8 b, float c) {
#if __has_builtin(__builtin_amdgcn_fdot2)
    const f16x2* pa = (const f16x2*)&a;
    const f16x2* pb = (const f16x2*)&b;
    c = __builtin_amdgcn_fdot2(pa[0], pb[0], c, false);
    c = __builtin_amdgcn_fdot2(pa[1], pb[1], c, false);
    c = __builtin_amdgcn_fdot2(pa[2], pb[2], c, false);
    c = __builtin_amdgcn_fdot2(pa[3], pb[3], c, false);
#else
    #pragma unroll
    for (int e = 0; e < 8; ++e) c += (float)a[e] * (float)b[e];
#endif
    return c;
}

// ---------------- Phase A: convert f32 -> fp16 (pre-swizzled) + exact norms --
// Also initializes packed32[] (+inf bits) and binfo[] (~0).
__global__ __launch_bounds__(256) void convert_kernel(
        const float* __restrict__ emb, const float* __restrict__ bank,
        _Float16* __restrict__ GAh, _Float16* __restrict__ GBh,
        float* __restrict__ x2, float* __restrict__ y2,
        unsigned* __restrict__ packed32, u64* __restrict__ binfo) {
    const int gid = blockIdx.x * 256 + threadIdx.x;
    if (gid < N_EMB) packed32[gid] = 0x7f800000u;   // +inf
    if (gid < BATCH) binfo[gid] = ~0ull;
    const int row = gid >> 4;
    const int chunk = gid & 15;
    const float* src;
    _Float16* dh;
    float* nrm;
    int R;
    if (row < M_BANK) {
        src = bank + (size_t)row * DIMD; dh = GBh; nrm = y2; R = row;
    } else {
        R = row - M_BANK;
        src = emb + (size_t)R * DIMD; dh = GAh; nrm = x2;
    }
    float4 v0 = ((const float4*)src)[chunk * 2];
    float4 v1 = ((const float4*)src)[chunk * 2 + 1];
    float f[8] = {v0.x, v0.y, v0.z, v0.w, v1.x, v1.y, v1.z, v1.w};
    f16x8 h;
    float s = 0.f;
    #pragma unroll
    for (int e = 0; e < 8; ++e) {
        h[e] = (_Float16)f[e];
        s += f[e] * f[e];
    }
    const int q = chunk >> 2, jj = chunk & 3;
    const int jj2 = jj ^ ((R >> 1) & 3);
    *(f16x8*)(dh + (size_t)R * DIMD + q * 32 + jj2 * 8) = h;
    #pragma unroll
    for (int off = 1; off < 16; off <<= 1) s += __shfl_xor(s, off, 16);
    if (chunk == 0) nrm[R] = s;
}

// ---------------- Phase B: MFMA approx dist^2, VALUE-ONLY row min -----------
// r19: 16 x 64-wide phases, 3 rotating 16KB LDS buffers, loads issued 2
// phases ahead, counted s_waitcnt vmcnt(4) + raw s_barrier per phase (never
// vmcnt(0) mid-loop). y2 chunk staged to LDS so fold does ds_reads only
// (keeps vmcnt accounting exact: gll16 is the ONLY VMEM op in the loop).

static __device__ __forceinline__ void stagePh(
        const _Float16* __restrict__ GBh, _Float16* dst,
        int mbase, int p, int srow, int se8) {
    const int mrow0 = mbase + (p >> 1) * 128;
    const int h = p & 1;
    #pragma unroll
    for (int j = 0; j < 2; ++j) {
        const int row = srow + j * 64;
        #pragma unroll
        for (int q = 0; q < 2; ++q)
            gll16(GBh + (size_t)(mrow0 + row) * DIMD + h * 64 + q * 32 + se8,
                  dst + q * 4096 + row * 32 + se8);
    }
}

template<int H, bool FIRST>
static __device__ __forceinline__ void computeB(
        const _Float16* bb, const f16x8 (&a)[4][4], f32x4 (&acc)[4][4],
        int wm, int g, int r16) {
    f16x8 b[4][2];
    #pragma unroll
    for (int fj = 0; fj < 4; ++fj) {
        const int row = wm * 64 + fj * 16 + r16;
        const int sw = (g ^ ((row >> 1) & 3)) << 3;
        b[fj][0] = *(const f16x8*)&bb[row * 32 + sw];
        b[fj][1] = *(const f16x8*)&bb[4096 + row * 32 + sw];
    }
    const f32x4 zero = {0.f, 0.f, 0.f, 0.f};
    #pragma unroll
    for (int ks = 0; ks < 2; ++ks)
        #pragma unroll
        for (int fi = 0; fi < 4; ++fi)
            #pragma unroll
            for (int fj = 0; fj < 4; ++fj)
                acc[fi][fj] = __builtin_amdgcn_mfma_f32_16x16x32_f16(
                    a[fi][2 * H + ks], b[fj][ks],
                    (FIRST && ks == 0) ? zero : acc[fi][fj], 0, 0, 0);
}

__global__ __launch_bounds__(256, 3) void dist_min_mfma(
        const _Float16* __restrict__ GAh, const _Float16* __restrict__ GBh,
        const float* __restrict__ x2, const float* __restrict__ y2,
        unsigned* __restrict__ packed32) {
    __shared__ _Float16 smem[26624];   // 52KB: 3x16KB B bufs | 4KB y2 slice
    float* sY = (float*)(smem + 24576);

    const int bid = blockIdx.x;
    const int c   = bid & 15;          // m-chunk; all its blocks on XCD c&7
    const int nt  = bid >> 4;          // 0..48
    const int n0  = nt * 128;
    const int mbase = c * 1024;

    const int tid  = threadIdx.x;
    const int lane = tid & 63;
    const int wid  = tid >> 6;
    const int wn = wid >> 1, wm = wid & 1;
    const int g = lane >> 4, r16 = lane & 15;
    const int srow = tid >> 2;
    const int se8  = (tid & 3) * 8;

    // ---- prologue: stage y2 slice (4KB) + A in two 16KB passes -> regs ----
    gll16((const _Float16*)(y2 + mbase) + (size_t)tid * 8, smem + 24576 + tid * 8);

    f16x8 a[4][4];
    #pragma unroll
    for (int h = 0; h < 2; ++h) {
        #pragma unroll
        for (int k = 0; k < 2; ++k)
            #pragma unroll
            for (int j = 0; j < 2; ++j) {
                const int row = srow + j * 64;
                gll16(GAh + (size_t)(n0 + row) * DIMD + (h * 2 + k) * 32 + se8,
                      smem + k * 4096 + row * 32 + se8);
            }
        __syncthreads();
        #pragma unroll
        for (int fi = 0; fi < 4; ++fi) {
            const int row = wn * 64 + fi * 16 + r16;
            const int sw = (g ^ ((row >> 1) & 3)) << 3;
            #pragma unroll
            for (int k = 0; k < 2; ++k)
                a[fi][h * 2 + k] = *(const f16x8*)&smem[k * 4096 + row * 32 + sw];
        }
        __syncthreads();               // done reading before region reuse
    }

    // ---- 16-phase pipelined B loop, 2 phases in flight ----
    stagePh(GBh, smem,        mbase, 0, srow, se8);
    stagePh(GBh, smem + 8192, mbase, 1, srow, se8);

    f32x4 acc[4][4];
    float runmin[4][4];
    #pragma unroll
    for (int fi = 0; fi < 4; ++fi)
        #pragma unroll
        for (int r = 0; r < 4; ++r) runmin[fi][r] = 3.4e38f;

    #pragma unroll
    for (int p = 0; p < 16; ++p) {
        if (p < 15) asm volatile("s_waitcnt vmcnt(4)" ::: "memory");
        else        asm volatile("s_waitcnt vmcnt(0)" ::: "memory");
        __builtin_amdgcn_s_barrier();          // phase p resident everywhere
        __builtin_amdgcn_sched_barrier(0);
        if (p + 2 < 16)
            stagePh(GBh, smem + ((p + 2) % 3) * 8192, mbase, p + 2, srow, se8);
        const _Float16* bb = smem + (p % 3) * 8192;
        if ((p & 1) == 0) {
            computeB<0, true>(bb, a, acc, wm, g, r16);
        } else {
            computeB<1, false>(bb, a, acc, wm, g, r16);
            // fold tile t = p>>1 (ys from LDS -> no VMEM in loop)
            const int tofs = (p >> 1) * 128 + wm * 64 + r16;
            float ys0 = sY[tofs +  0], ys1 = sY[tofs + 16];
            float ys2 = sY[tofs + 32], ys3 = sY[tofs + 48];
            #pragma unroll
            for (int fi = 0; fi < 4; ++fi)
                #pragma unroll
                for (int r = 0; r < 4; ++r) {
                    float d0 = fmaf(-2.f, acc[fi][0][r], ys0);
                    float d1 = fmaf(-2.f, acc[fi][1][r], ys1);
                    float d2v = fmaf(-2.f, acc[fi][2][r], ys2);
                    float d3 = fmaf(-2.f, acc[fi][3][r], ys3);
                    runmin[fi][r] = fminf(runmin[fi][r],
                                          fminf(fminf(d0, d1), fminf(d2v, d3)));
                }
        }
    }

    // ---- epilogue: add xs, clamp, 16-lane float min reduce, u32 atomicMin --
    #pragma unroll
    for (int fi = 0; fi < 4; ++fi) {
        #pragma unroll
        for (int r = 0; r < 4; ++r) {
            const int n = n0 + wn * 64 + fi * 16 + g * 4 + r;
            float v = runmin[fi][r];
            #pragma unroll
            for (int off = 1; off < 16; off <<= 1)
                v = fminf(v, __shfl_xor(v, off));
            if (r16 == 0) {
                float d2 = fmaxf(x2[n] + v, EPSF);
                atomicMin(&packed32[n], __float_as_uint(d2));
            }
        }
    }
}

// ------- Phase C0: nn argmin for the 8 chosen patches (fp16 scan) -----------
// MEASURED r17 -- byte-identical.
__global__ __launch_bounds__(256) void nn_find(
        const unsigned* __restrict__ packed32,
        const _Float16* __restrict__ GAh, const _Float16* __restrict__ GBh,
        const float* __restrict__ x2, const float* __restrict__ y2,
        u64* __restrict__ binfo, unsigned* __restrict__ pstar) {
    const int b = blockIdx.y, tid = threadIdx.x;
    __shared__ u64 red[256];
    __shared__ unsigned s_p;
    __shared__ _Float16 xv[DIMD];

    u64 bk = 0;
    for (int p = tid; p < PPB; p += 256) {
        unsigned bits = packed32[(size_t)b * PPB + p];
        bk = umax64(bk, ((u64)bits << 32) | (u64)(0xFFFFFFFFu - (unsigned)p));
    }
    red[tid] = bk; __syncthreads();
    for (int s = 128; s; s >>= 1) {
        if (tid < s) red[tid] = umax64(red[tid], red[tid + s]);
        __syncthreads();
    }
    if (tid == 0) s_p = 0xFFFFFFFFu - (unsigned)red[0];
    __syncthreads();
    const unsigned p = s_p;
    if (blockIdx.x == 0 && tid == 0) pstar[b] = p;

    const int Ra = b * PPB + (int)p;
    if (tid < DIMD) xv[tid] = GAh[(size_t)Ra * DIMD + tid];
    const float xr2 = x2[Ra];
    __syncthreads();

    const int m = blockIdx.x * 256 + tid;
    const int delta = (((Ra >> 1) ^ (m >> 1)) & 3);
    const _Float16* row = GBh + (size_t)m * DIMD;
    float dot = 0.f;
    #pragma unroll
    for (int q = 0; q < 4; ++q)
        #pragma unroll
        for (int jj2 = 0; jj2 < 4; ++jj2) {
            f16x8 ym = *(const f16x8*)(row + q * 32 + jj2 * 8);
            f16x8 xm = *(const f16x8*)&xv[q * 32 + (jj2 ^ delta) * 8];
            dot = dot8(ym, xm, dot);
        }
    float d2 = fmaxf(xr2 + y2[m] - 2.0f * dot, EPSF);
    u64 key = ((u64)__float_as_uint(d2) << 32) | (unsigned)m;
    red[tid] = key; __syncthreads();
    for (int s = 128; s; s >>= 1) {
        if (tid < s) red[tid] = umin64(red[tid], red[tid + s]);
        __syncthreads();
    }
    if (tid == 0) atomicMin(&binfo[b], red[0]);
}

// ------- Phase C1: knn scan, grid (NKB, BATCH) -- MEASURED r17 --------------
__global__ __launch_bounds__(256) void knn_kernel(
        const u64* __restrict__ binfo,
        const _Float16* __restrict__ GBh,
        const float* __restrict__ y2,
        u64* __restrict__ cand) {
    const int b = blockIdx.y, tid = threadIdx.x;
    __shared__ u64 red4[4];
    __shared__ u64 s_wkey;
    __shared__ _Float16 nv[DIMD];

    const unsigned nn = (unsigned)binfo[b];
    if (tid < DIMD) nv[tid] = GBh[(size_t)nn * DIMD + tid];
    __syncthreads();

    const int m = blockIdx.x * 256 + tid;
    const int delta = (((nn >> 1) ^ (m >> 1)) & 3);
    const _Float16* row = GBh + (size_t)m * DIMD;
    float dot = 0.f;
    #pragma unroll
    for (int q = 0; q < 4; ++q)
        #pragma unroll
        for (int jj2 = 0; jj2 < 4; ++jj2) {
            f16x8 ym = *(const f16x8*)(row + q * 32 + jj2 * 8);
            f16x8 xm = *(const f16x8*)&nv[q * 32 + (jj2 ^ delta) * 8];
            dot = dot8(ym, xm, dot);
        }
    float d2 = fmaxf(y2[nn] + y2[m] - 2.0f * dot, EPSF);
    const u64 mykey = ((u64)__float_as_uint(d2) << 32) | (unsigned)m;

    u64* myout = cand + ((size_t)b * NKB + blockIdx.x) * KNN;
    bool used = false;
    for (int r = 0; r < KNN; ++r) {
        u64 h = used ? ~0ull : mykey;
        #pragma unroll
        for (int off = 1; off < 64; off <<= 1)
            h = umin64(h, (u64)__shfl_xor((unsigned long long)h, off));
        if ((tid & 63) == 0) red4[tid >> 6] = h;
        __syncthreads();
        if (tid == 0) {
            u64 w = umin64(umin64(red4[0], red4[1]), umin64(red4[2], red4[3]));
            s_wkey = w;
            myout[r] = w;
        }
        __syncthreads();
        if (!used && mykey == s_wkey) used = true;
    }
}

// ------- Phase C2: merge candidates + exact rescore + softmax (8 blocks) ----
// MEASURED r17 -- byte-identical.
__global__ __launch_bounds__(256) void final_kernel(
        const float* __restrict__ emb, const float* __restrict__ bank,
        const float* __restrict__ x2, const float* __restrict__ y2,
        const u64* __restrict__ binfo, const unsigned* __restrict__ pstar,
        const u64* __restrict__ cand,
        float* __restrict__ out) {
    const int b = blockIdx.x, tid = threadIdx.x;
    __shared__ u64 lists[256 * 3];
    __shared__ float fred[256];
    __shared__ u64 red4[4];
    __shared__ u64 s_wkey;
    __shared__ unsigned s_sel[KNN];
    __shared__ float s_dist[KNN];
    __shared__ float xv[DIMD];

    const unsigned p = pstar[b];
    const unsigned nn = (unsigned)binfo[b];

    float prod = 0.f;
    if (tid < DIMD) {
        float xvv = emb[(size_t)(b * PPB + p) * DIMD + tid];
        xv[tid] = xvv;
        prod = xvv * bank[(size_t)nn * DIMD + tid];
    }
    fred[tid] = prod; __syncthreads();
    for (int s = 128; s; s >>= 1) {
        if (tid < s) fred[tid] += fred[tid + s];
        __syncthreads();
    }
    const float d2star = fmaxf(x2[b * PPB + p] + y2[nn] - 2.0f * fred[0], EPSF);

    u64 lst[3] = {~0ull, ~0ull, ~0ull};
    #pragma unroll
    for (int i = 0; i < 3; ++i) {
        const int idx = tid * 3 + i;
        if (idx < NKB * KNN) {
            u64 k = cand[(size_t)b * NKB * KNN + idx];
            lst[2] = k;
            u64 a0 = lst[0], a1 = lst[1], a2 = lst[2];
            u64 t01l = umin64(a0, a1), t01h = umax64(a0, a1);
            u64 m2 = umin64(t01h, a2), h2 = umax64(t01h, a2);
            lst[0] = umin64(t01l, m2);
            lst[1] = umax64(t01l, m2);
            lst[2] = h2;
        }
    }
    lists[tid * 3 + 0] = lst[0];
    lists[tid * 3 + 1] = lst[1];
    lists[tid * 3 + 2] = lst[2];
    __syncthreads();

    int pp = 0;
    for (int r = 0; r < KNN; ++r) {
        u64 h = (pp < 3) ? lists[tid * 3 + pp] : ~0ull;
        #pragma unroll
        for (int off = 1; off < 64; off <<= 1)
            h = umin64(h, (u64)__shfl_xor((unsigned long long)h, off));
        if ((tid & 63) == 0) red4[tid >> 6] = h;
        __syncthreads();
        if (tid == 0) {
            u64 w = umin64(umin64(red4[0], red4[1]), umin64(red4[2], red4[3]));
            s_wkey = w;
            s_sel[r] = (unsigned)w;
        }
        __syncthreads();
        const u64 w = s_wkey;
        if (pp < 3 && lists[tid * 3 + pp] == w) ++pp;
    }

    // exact fp32 distances for the 9 selected (order of 1..8 irrelevant:
    // output uses element 0 (self-match) + order-invariant sum)
    if (tid < KNN) {
        const unsigned s = s_sel[tid];
        const float* srow = bank + (size_t)s * DIMD;
        float dot = 0.f;
        for (int d = 0; d < DIMD; ++d) dot += srow[d] * xv[d];
        float d2 = x2[b * PPB + p] + y2[s] - 2.0f * dot;
        s_dist[tid] = sqrtf(fmaxf(d2, EPSF));
    }
    __syncthreads();

    if (tid == 0) {
        float mx = s_dist[0];
        for (int i = 1; i < KNN; ++i) mx = fmaxf(mx, s_dist[i]);
        float sum = 0.f, e0 = 0.f;
        for (int i = 0; i < KNN; ++i) {
            float e = expf(s_dist[i] - mx);
            sum += e;
            if (i == 0) e0 = e;
        }
        float w = 1.0f - e0 / sum;
        out[b] = w * sqrtf(d2star);
    }
}

extern "C" void kernel_launch(void* const* d_in, const int* in_sizes, int n_in,
                              void* d_out, int out_size, void* d_ws, size_t ws_size,
                              hipStream_t stream) {
    const float* emb  = (const float*)d_in[0];
    const float* bank = (const float*)d_in[1];
    float* out = (float*)d_out;

    char* ws = (char*)d_ws;
    unsigned* packed32 = (unsigned*) (ws + 0);        //  25088 B
    float*    x2       = (float*)    (ws + 32768);    //  25088 B
    float*    y2       = (float*)    (ws + 65536);    //  65536 B
    u64*      binfo    = (u64*)      (ws + 131072);   //     64 B
    unsigned* pstar    = (unsigned*) (ws + 131200);   //     32 B
    u64*      cand     = (u64*)      (ws + 135168);   //  36864 B
    _Float16* GAh      = (_Float16*) (ws + 262144);   // 1605632 B
    _Float16* GBh      = (_Float16*) (ws + 1867776);  // 4194304 B (end 6062080)

    {
        const int rows = M_BANK + N_EMB;             // 22656
        const int blocks = rows * 16 / 256;          // 1416
        convert_kernel<<<blocks, 256, 0, stream>>>(emb, bank, GAh, GBh, x2, y2,
                                                   packed32, binfo);
    }

    dist_min_mfma<<<49 * 16, 256, 0, stream>>>(GAh, GBh, x2, y2, packed32);

    nn_find<<<dim3(NKB, BATCH), 256, 0, stream>>>(packed32, GAh, GBh, x2, y2,
                                                  binfo, pstar);

    knn_kernel<<<dim3(NKB, BATCH), 256, 0, stream>>>(binfo, GBh, y2, cand);

    final_kernel<<<BATCH, 256, 0, stream>>>(emb, bank, x2, y2, binfo, pstar,
                                            cand, out);
}

// Round 20
// 79.930 us; speedup vs baseline: 4.9110x; 4.9110x over previous
//
#include <hip/hip_runtime.h>
#include <cstdint>

#define N_EMB 6272      // B*W*H = 8*28*28
#define DIMD  128
#define M_BANK 16384
#define BATCH 8
#define PPB   784       // patches per batch
#define KNN   9
#define EPSF  1e-12f
#define NKB   64        // scan blocks per batch (nn_find / knn)

typedef unsigned long long u64;
typedef _Float16 f16x8 __attribute__((ext_vector_type(8)));
typedef _Float16 f16x2 __attribute__((ext_vector_type(2)));
typedef float    f32x4 __attribute__((ext_vector_type(4)));

static __device__ __forceinline__ u64 umin64(u64 a, u64 b) { return b < a ? b : a; }
static __device__ __forceinline__ u64 umax64(u64 a, u64 b) { return b > a ? b : a; }

// async global->LDS, 16B per lane, linear LDS dest (wave-uniform base + lane*16)
static __device__ __forceinline__ void gll16(const _Float16* g, _Float16* l) {
    __builtin_amdgcn_global_load_lds(
        (__attribute__((address_space(1))) void*)(const void*)g,
        (__attribute__((address_space(3))) void*)l, 16, 0, 0);
}

// packed fp16 dot: 8 elems into fp32 accumulator
static __device__ __forceinline__ float dot8(f16x8 a, f16x8 b, float c) {
#if __has_builtin(__builtin_amdgcn_fdot2)
    const f16x2* pa = (const f16x2*)&a;
    const f16x2* pb = (const f16x2*)&b;
    c = __builtin_amdgcn_fdot2(pa[0], pb[0], c, false);
    c = __builtin_amdgcn_fdot2(pa[1], pb[1], c, false);
    c = __builtin_amdgcn_fdot2(pa[2], pb[2], c, false);
    c = __builtin_amdgcn_fdot2(pa[3], pb[3], c, false);
#else
    #pragma unroll
    for (int e = 0; e < 8; ++e) c += (float)a[e] * (float)b[e];
#endif
    return c;
}

// ---------------- Phase A: convert f32 -> fp16 (pre-swizzled) + exact norms --
// Also initializes packed32[] (+inf bits) and binfo[] (~0).
__global__ __launch_bounds__(256) void convert_kernel(
        const float* __restrict__ emb, const float* __restrict__ bank,
        _Float16* __restrict__ GAh, _Float16* __restrict__ GBh,
        float* __restrict__ x2, float* __restrict__ y2,
        unsigned* __restrict__ packed32, u64* __restrict__ binfo) {
    const int gid = blockIdx.x * 256 + threadIdx.x;
    if (gid < N_EMB) packed32[gid] = 0x7f800000u;   // +inf
    if (gid < BATCH) binfo[gid] = ~0ull;
    const int row = gid >> 4;
    const int chunk = gid & 15;
    const float* src;
    _Float16* dh;
    float* nrm;
    int R;
    if (row < M_BANK) {
        src = bank + (size_t)row * DIMD; dh = GBh; nrm = y2; R = row;
    } else {
        R = row - M_BANK;
        src = emb + (size_t)R * DIMD; dh = GAh; nrm = x2;
    }
    float4 v0 = ((const float4*)src)[chunk * 2];
    float4 v1 = ((const float4*)src)[chunk * 2 + 1];
    float f[8] = {v0.x, v0.y, v0.z, v0.w, v1.x, v1.y, v1.z, v1.w};
    f16x8 h;
    float s = 0.f;
    #pragma unroll
    for (int e = 0; e < 8; ++e) {
        h[e] = (_Float16)f[e];
        s += f[e] * f[e];
    }
    const int q = chunk >> 2, jj = chunk & 3;
    const int jj2 = jj ^ ((R >> 1) & 3);
    *(f16x8*)(dh + (size_t)R * DIMD + q * 32 + jj2 * 8) = h;
    #pragma unroll
    for (int off = 1; off < 16; off <<= 1) s += __shfl_xor(s, off, 16);
    if (chunk == 0) nrm[R] = s;
}

// ---------------- Phase B: MFMA approx dist^2, VALUE-ONLY row min -----------
// r20: r15 loop shape, but raw s_barrier + COUNTED s_waitcnt vmcnt(4)
// (never vmcnt(0) mid-loop) so the prefetched half-tile stays in flight
// across barriers. y2 slice staged to LDS so gll16 is the loop's only VMEM
// op (exact vmcnt accounting). LDS 36KB; launch_bounds(256,2) (no-spill cfg).

static __device__ __forceinline__ void stageB(
        const _Float16* __restrict__ GBh, _Float16* dst,
        int mrow0, int h, int srow, int se8) {
    #pragma unroll
    for (int j = 0; j < 2; ++j) {
        const int row = srow + j * 64;
        #pragma unroll
        for (int q = 0; q < 2; ++q)
            gll16(GBh + (size_t)(mrow0 + row) * DIMD + h * 64 + q * 32 + se8,
                  dst + q * 4096 + row * 32 + se8);
    }
}

template<int H, bool FIRST>
static __device__ __forceinline__ void computeB(
        const _Float16* bb, const f16x8 (&a)[4][4], f32x4 (&acc)[4][4],
        int wm, int g, int r16) {
    f16x8 b[4][2];
    #pragma unroll
    for (int fj = 0; fj < 4; ++fj) {
        const int row = wm * 64 + fj * 16 + r16;
        const int sw = (g ^ ((row >> 1) & 3)) << 3;
        b[fj][0] = *(const f16x8*)&bb[row * 32 + sw];
        b[fj][1] = *(const f16x8*)&bb[4096 + row * 32 + sw];
    }
    const f32x4 zero = {0.f, 0.f, 0.f, 0.f};
    #pragma unroll
    for (int ks = 0; ks < 2; ++ks)
        #pragma unroll
        for (int fi = 0; fi < 4; ++fi)
            #pragma unroll
            for (int fj = 0; fj < 4; ++fj)
                acc[fi][fj] = __builtin_amdgcn_mfma_f32_16x16x32_f16(
                    a[fi][2 * H + ks], b[fj][ks],
                    (FIRST && ks == 0) ? zero : acc[fi][fj], 0, 0, 0);
}

__global__ __launch_bounds__(256, 2) void dist_min_mfma(
        const _Float16* __restrict__ GAh, const _Float16* __restrict__ GBh,
        const float* __restrict__ x2, const float* __restrict__ y2,
        unsigned* __restrict__ packed32) {
    __shared__ _Float16 smem[18432];   // 36KB: B0(16K) | B1(16K) | y2 slice(4K)
    float* sY = (float*)(smem + 16384);

    const int bid = blockIdx.x;
    const int c   = bid & 15;          // m-chunk; all its blocks on XCD c&7
    const int nt  = bid >> 4;          // 0..48
    const int n0  = nt * 128;
    const int mbase = c * 1024;

    const int tid  = threadIdx.x;
    const int lane = tid & 63;
    const int wid  = tid >> 6;
    const int wn = wid >> 1, wm = wid & 1;
    const int g = lane >> 4, r16 = lane & 15;
    const int srow = tid >> 2;
    const int se8  = (tid & 3) * 8;

    _Float16* sB0 = smem;
    _Float16* sB1 = smem + 8192;

    // ---- prologue: y2 slice + A in two 16KB passes via sB0 region -> regs --
    gll16((const _Float16*)(y2 + mbase) + (size_t)tid * 8, smem + 16384 + tid * 8);

    f16x8 a[4][4];
    #pragma unroll
    for (int h = 0; h < 2; ++h) {
        #pragma unroll
        for (int k = 0; k < 2; ++k)
            #pragma unroll
            for (int j = 0; j < 2; ++j) {
                const int row = srow + j * 64;
                gll16(GAh + (size_t)(n0 + row) * DIMD + (h * 2 + k) * 32 + se8,
                      smem + k * 4096 + row * 32 + se8);
            }
        __syncthreads();
        #pragma unroll
        for (int fi = 0; fi < 4; ++fi) {
            const int row = wn * 64 + fi * 16 + r16;
            const int sw = (g ^ ((row >> 1) & 3)) << 3;
            #pragma unroll
            for (int k = 0; k < 2; ++k)
                a[fi][h * 2 + k] = *(const f16x8*)&smem[k * 4096 + row * 32 + sw];
        }
        __syncthreads();               // done reading before region reuse
    }

    stageB(GBh, sB0, mbase, 0, srow, se8);   // t=0 k-half 0 in flight (4 loads)

    f32x4 acc[4][4];
    float runmin[4][4];
    #pragma unroll
    for (int fi = 0; fi < 4; ++fi)
        #pragma unroll
        for (int r = 0; r < 4; ++r) runmin[fi][r] = 3.4e38f;

    for (int t = 0; t < 8; ++t) {
        const int mt = mbase + t * 128;
        __builtin_amdgcn_s_barrier();               // D: sB1 safe to overwrite
        __builtin_amdgcn_sched_barrier(0);
        stageB(GBh, sB1, mt, 1, srow, se8);         // out: sB0(t)+sB1(t) = 8
        asm volatile("s_waitcnt vmcnt(4)" ::: "memory");   // own sB0(t) landed
        __builtin_amdgcn_s_barrier();               // A: sB0(t) resident (all)
        __builtin_amdgcn_sched_barrier(0);
        computeB<0, true>(sB0, a, acc, wm, g, r16);
        __builtin_amdgcn_s_barrier();               // B: sB0 safe to overwrite
        __builtin_amdgcn_sched_barrier(0);
        if (t < 7) {
            stageB(GBh, sB0, mt + 128, 0, srow, se8);      // out: sB1+sB0' = 8
            asm volatile("s_waitcnt vmcnt(4)" ::: "memory"); // own sB1 landed
        } else {
            asm volatile("s_waitcnt vmcnt(0)" ::: "memory");
        }
        __builtin_amdgcn_s_barrier();               // C: sB1(t) resident (all)
        __builtin_amdgcn_sched_barrier(0);
        computeB<1, false>(sB1, a, acc, wm, g, r16);

        // value-only fold; ys from LDS (no VMEM in loop body)
        const int tofs = t * 128 + wm * 64 + r16;
        const float ys0 = sY[tofs +  0], ys1 = sY[tofs + 16];
        const float ys2 = sY[tofs + 32], ys3 = sY[tofs + 48];
        #pragma unroll
        for (int fi = 0; fi < 4; ++fi)
            #pragma unroll
            for (int r = 0; r < 4; ++r) {
                float d0 = fmaf(-2.f, acc[fi][0][r], ys0);
                float d1 = fmaf(-2.f, acc[fi][1][r], ys1);
                float d2v = fmaf(-2.f, acc[fi][2][r], ys2);
                float d3 = fmaf(-2.f, acc[fi][3][r], ys3);
                runmin[fi][r] = fminf(runmin[fi][r],
                                      fminf(fminf(d0, d1), fminf(d2v, d3)));
            }
    }

    // ---- epilogue: add xs, clamp, 16-lane float min reduce, u32 atomicMin --
    #pragma unroll
    for (int fi = 0; fi < 4; ++fi) {
        #pragma unroll
        for (int r = 0; r < 4; ++r) {
            const int n = n0 + wn * 64 + fi * 16 + g * 4 + r;
            float v = runmin[fi][r];
            #pragma unroll
            for (int off = 1; off < 16; off <<= 1)
                v = fminf(v, __shfl_xor(v, off));
            if (r16 == 0) {
                float d2 = fmaxf(x2[n] + v, EPSF);
                atomicMin(&packed32[n], __float_as_uint(d2));
            }
        }
    }
}

// ------- Phase C0: nn argmin for the 8 chosen patches (fp16 scan) -----------
// MEASURED r17 -- byte-identical.
__global__ __launch_bounds__(256) void nn_find(
        const unsigned* __restrict__ packed32,
        const _Float16* __restrict__ GAh, const _Float16* __restrict__ GBh,
        const float* __restrict__ x2, const float* __restrict__ y2,
        u64* __restrict__ binfo, unsigned* __restrict__ pstar) {
    const int b = blockIdx.y, tid = threadIdx.x;
    __shared__ u64 red[256];
    __shared__ unsigned s_p;
    __shared__ _Float16 xv[DIMD];

    u64 bk = 0;
    for (int p = tid; p < PPB; p += 256) {
        unsigned bits = packed32[(size_t)b * PPB + p];
        bk = umax64(bk, ((u64)bits << 32) | (u64)(0xFFFFFFFFu - (unsigned)p));
    }
    red[tid] = bk; __syncthreads();
    for (int s = 128; s; s >>= 1) {
        if (tid < s) red[tid] = umax64(red[tid], red[tid + s]);
        __syncthreads();
    }
    if (tid == 0) s_p = 0xFFFFFFFFu - (unsigned)red[0];
    __syncthreads();
    const unsigned p = s_p;
    if (blockIdx.x == 0 && tid == 0) pstar[b] = p;

    const int Ra = b * PPB + (int)p;
    if (tid < DIMD) xv[tid] = GAh[(size_t)Ra * DIMD + tid];
    const float xr2 = x2[Ra];
    __syncthreads();

    const int m = blockIdx.x * 256 + tid;
    const int delta = (((Ra >> 1) ^ (m >> 1)) & 3);
    const _Float16* row = GBh + (size_t)m * DIMD;
    float dot = 0.f;
    #pragma unroll
    for (int q = 0; q < 4; ++q)
        #pragma unroll
        for (int jj2 = 0; jj2 < 4; ++jj2) {
            f16x8 ym = *(const f16x8*)(row + q * 32 + jj2 * 8);
            f16x8 xm = *(const f16x8*)&xv[q * 32 + (jj2 ^ delta) * 8];
            dot = dot8(ym, xm, dot);
        }
    float d2 = fmaxf(xr2 + y2[m] - 2.0f * dot, EPSF);
    u64 key = ((u64)__float_as_uint(d2) << 32) | (unsigned)m;
    red[tid] = key; __syncthreads();
    for (int s = 128; s; s >>= 1) {
        if (tid < s) red[tid] = umin64(red[tid], red[tid + s]);
        __syncthreads();
    }
    if (tid == 0) atomicMin(&binfo[b], red[0]);
}

// ------- Phase C1: knn scan, grid (NKB, BATCH) -- MEASURED r17 --------------
__global__ __launch_bounds__(256) void knn_kernel(
        const u64* __restrict__ binfo,
        const _Float16* __restrict__ GBh,
        const float* __restrict__ y2,
        u64* __restrict__ cand) {
    const int b = blockIdx.y, tid = threadIdx.x;
    __shared__ u64 red4[4];
    __shared__ u64 s_wkey;
    __shared__ _Float16 nv[DIMD];

    const unsigned nn = (unsigned)binfo[b];
    if (tid < DIMD) nv[tid] = GBh[(size_t)nn * DIMD + tid];
    __syncthreads();

    const int m = blockIdx.x * 256 + tid;
    const int delta = (((nn >> 1) ^ (m >> 1)) & 3);
    const _Float16* row = GBh + (size_t)m * DIMD;
    float dot = 0.f;
    #pragma unroll
    for (int q = 0; q < 4; ++q)
        #pragma unroll
        for (int jj2 = 0; jj2 < 4; ++jj2) {
            f16x8 ym = *(const f16x8*)(row + q * 32 + jj2 * 8);
            f16x8 xm = *(const f16x8*)&nv[q * 32 + (jj2 ^ delta) * 8];
            dot = dot8(ym, xm, dot);
        }
    float d2 = fmaxf(y2[nn] + y2[m] - 2.0f * dot, EPSF);
    const u64 mykey = ((u64)__float_as_uint(d2) << 32) | (unsigned)m;

    u64* myout = cand + ((size_t)b * NKB + blockIdx.x) * KNN;
    bool used = false;
    for (int r = 0; r < KNN; ++r) {
        u64 h = used ? ~0ull : mykey;
        #pragma unroll
        for (int off = 1; off < 64; off <<= 1)
            h = umin64(h, (u64)__shfl_xor((unsigned long long)h, off));
        if ((tid & 63) == 0) red4[tid >> 6] = h;
        __syncthreads();
        if (tid == 0) {
            u64 w = umin64(umin64(red4[0], red4[1]), umin64(red4[2], red4[3]));
            s_wkey = w;
            myout[r] = w;
        }
        __syncthreads();
        if (!used && mykey == s_wkey) used = true;
    }
}

// ------- Phase C2: merge candidates + exact rescore + softmax (8 blocks) ----
// MEASURED r17 -- byte-identical.
__global__ __launch_bounds__(256) void final_kernel(
        const float* __restrict__ emb, const float* __restrict__ bank,
        const float* __restrict__ x2, const float* __restrict__ y2,
        const u64* __restrict__ binfo, const unsigned* __restrict__ pstar,
        const u64* __restrict__ cand,
        float* __restrict__ out) {
    const int b = blockIdx.x, tid = threadIdx.x;
    __shared__ u64 lists[256 * 3];
    __shared__ float fred[256];
    __shared__ u64 red4[4];
    __shared__ u64 s_wkey;
    __shared__ unsigned s_sel[KNN];
    __shared__ float s_dist[KNN];
    __shared__ float xv[DIMD];

    const unsigned p = pstar[b];
    const unsigned nn = (unsigned)binfo[b];

    float prod = 0.f;
    if (tid < DIMD) {
        float xvv = emb[(size_t)(b * PPB + p) * DIMD + tid];
        xv[tid] = xvv;
        prod = xvv * bank[(size_t)nn * DIMD + tid];
    }
    fred[tid] = prod; __syncthreads();
    for (int s = 128; s; s >>= 1) {
        if (tid < s) fred[tid] += fred[tid + s];
        __syncthreads();
    }
    const float d2star = fmaxf(x2[b * PPB + p] + y2[nn] - 2.0f * fred[0], EPSF);

    u64 lst[3] = {~0ull, ~0ull, ~0ull};
    #pragma unroll
    for (int i = 0; i < 3; ++i) {
        const int idx = tid * 3 + i;
        if (idx < NKB * KNN) {
            u64 k = cand[(size_t)b * NKB * KNN + idx];
            lst[2] = k;
            u64 a0 = lst[0], a1 = lst[1], a2 = lst[2];
            u64 t01l = umin64(a0, a1), t01h = umax64(a0, a1);
            u64 m2 = umin64(t01h, a2), h2 = umax64(t01h, a2);
            lst[0] = umin64(t01l, m2);
            lst[1] = umax64(t01l, m2);
            lst[2] = h2;
        }
    }
    lists[tid * 3 + 0] = lst[0];
    lists[tid * 3 + 1] = lst[1];
    lists[tid * 3 + 2] = lst[2];
    __syncthreads();

    int pp = 0;
    for (int r = 0; r < KNN; ++r) {
        u64 h = (pp < 3) ? lists[tid * 3 + pp] : ~0ull;
        #pragma unroll
        for (int off = 1; off < 64; off <<= 1)
            h = umin64(h, (u64)__shfl_xor((unsigned long long)h, off));
        if ((tid & 63) == 0) red4[tid >> 6] = h;
        __syncthreads();
        if (tid == 0) {
            u64 w = umin64(umin64(red4[0], red4[1]), umin64(red4[2], red4[3]));
            s_wkey = w;
            s_sel[r] = (unsigned)w;
        }
        __syncthreads();
        const u64 w = s_wkey;
        if (pp < 3 && lists[tid * 3 + pp] == w) ++pp;
    }

    // exact fp32 distances for the 9 selected (order of 1..8 irrelevant:
    // output uses element 0 (self-match) + order-invariant sum)
    if (tid < KNN) {
        const unsigned s = s_sel[tid];
        const float* srow = bank + (size_t)s * DIMD;
        float dot = 0.f;
        for (int d = 0; d < DIMD; ++d) dot += srow[d] * xv[d];
        float d2 = x2[b * PPB + p] + y2[s] - 2.0f * dot;
        s_dist[tid] = sqrtf(fmaxf(d2, EPSF));
    }
    __syncthreads();

    if (tid == 0) {
        float mx = s_dist[0];
        for (int i = 1; i < KNN; ++i) mx = fmaxf(mx, s_dist[i]);
        float sum = 0.f, e0 = 0.f;
        for (int i = 0; i < KNN; ++i) {
            float e = expf(s_dist[i] - mx);
            sum += e;
            if (i == 0) e0 = e;
        }
        float w = 1.0f - e0 / sum;
        out[b] = w * sqrtf(d2star);
    }
}

extern "C" void kernel_launch(void* const* d_in, const int* in_sizes, int n_in,
                              void* d_out, int out_size, void* d_ws, size_t ws_size,
                              hipStream_t stream) {
    const float* emb  = (const float*)d_in[0];
    const float* bank = (const float*)d_in[1];
    float* out = (float*)d_out;

    char* ws = (char*)d_ws;
    unsigned* packed32 = (unsigned*) (ws + 0);        //  25088 B
    float*    x2       = (float*)    (ws + 32768);    //  25088 B
    float*    y2       = (float*)    (ws + 65536);    //  65536 B
    u64*      binfo    = (u64*)      (ws + 131072);   //     64 B
    unsigned* pstar    = (unsigned*) (ws + 131200);   //     32 B
    u64*      cand     = (u64*)      (ws + 135168);   //  36864 B
    _Float16* GAh      = (_Float16*) (ws + 262144);   // 1605632 B
    _Float16* GBh      = (_Float16*) (ws + 1867776);  // 4194304 B (end 6062080)

    {
        const int rows = M_BANK + N_EMB;             // 22656
        const int blocks = rows * 16 / 256;          // 1416
        convert_kernel<<<blocks, 256, 0, stream>>>(emb, bank, GAh, GBh, x2, y2,
                                                   packed32, binfo);
    }

    dist_min_mfma<<<49 * 16, 256, 0, stream>>>(GAh, GBh, x2, y2, packed32);

    nn_find<<<dim3(NKB, BATCH), 256, 0, stream>>>(packed32, GAh, GBh, x2, y2,
                                                  binfo, pstar);

    knn_kernel<<<dim3(NKB, BATCH), 256, 0, stream>>>(binfo, GBh, y2, cand);

    final_kernel<<<BATCH, 256, 0, stream>>>(emb, bank, x2, y2, binfo, pstar,
                                            cand, out);
}